// Round 7
// baseline (109.067 us; speedup 1.0000x reference)
//
#include <hip/hip_runtime.h>
#include <hip/hip_bf16.h>

// SpecAugment: out = (x + noise*0.04) masked by per-sample freq/time zero masks.
// x, noise: [B=128, C=3, F=128, T=1000] f32. f0/f_len: [B,2], t0/t_len: [B,2] i32.
// Memory-bound. Empirical gradient (R1/R5/R4): more, smaller blocks win.
// This round: 128-thread block per HALF-row (98304 blocks, 2 waves/block) —
// less per-block tail-drain than 4-wave blocks, same contiguous access.
// Normal stores (nt measured -4us on this structure in R6).

#define B 128
#define C 3
#define Fd 128
#define T 1000
#define NOISE_STD 0.04f

typedef float  f32x4 __attribute__((ext_vector_type(4)));
typedef int    i32x2 __attribute__((ext_vector_type(2)));

constexpr int ROWS        = B * C * Fd;   // 49152
constexpr int V4_PER_ROW  = T / 4;        // 250
constexpr int V4_PER_HALF = V4_PER_ROW / 2;  // 125
constexpr int NBLOCKS     = ROWS * 2;     // 98304

__global__ __launch_bounds__(128) void specaug_kernel(
    const float* __restrict__ x, const float* __restrict__ noise,
    const int* __restrict__ f0, const int* __restrict__ f_len,
    const int* __restrict__ t0, const int* __restrict__ t_len,
    float* __restrict__ out)
{
    const int bid  = blockIdx.x;
    const int row  = bid >> 1;               // [0, ROWS)
    const int half = bid & 1;
    const int f    = row & (Fd - 1);         // row % 128
    const int b    = row / (C * Fd);
    const int tid  = threadIdx.x;            // 0..127; 125 active

    if (tid >= V4_PER_HALF) return;

    const i32x2 fa = reinterpret_cast<const i32x2*>(f0)[b];
    const i32x2 fl = reinterpret_cast<const i32x2*>(f_len)[b];
    const bool fmask = (f >= fa.x && f < fa.x + fl.x) ||
                       (f >= fa.y && f < fa.y + fl.y);

    const long long base = (long long)row * V4_PER_ROW + half * V4_PER_HALF + tid;
    f32x4* outp = reinterpret_cast<f32x4*>(out) + base;

    if (fmask) {
        // Whole row zeroed — skip both input reads.
        f32x4 z = {0.f, 0.f, 0.f, 0.f};
        *outp = z;
        return;
    }

    const i32x2 ta = reinterpret_cast<const i32x2*>(t0)[b];
    const i32x2 tl = reinterpret_cast<const i32x2*>(t_len)[b];

    const f32x4 xv = reinterpret_cast<const f32x4*>(x)[base];
    const f32x4 nv = reinterpret_cast<const f32x4*>(noise)[base];

    const int t = (half * V4_PER_HALF + tid) * 4;
    f32x4 ov;
#pragma unroll
    for (int k = 0; k < 4; ++k) {
        const int tt = t + k;
        const bool tmask = (tt >= ta.x && tt < ta.x + tl.x) ||
                           (tt >= ta.y && tt < ta.y + tl.y);
        ov[k] = tmask ? 0.f : fmaf(nv[k], NOISE_STD, xv[k]);
    }
    *outp = ov;
}

extern "C" void kernel_launch(void* const* d_in, const int* in_sizes, int n_in,
                              void* d_out, int out_size, void* d_ws, size_t ws_size,
                              hipStream_t stream)
{
    const float* x     = (const float*)d_in[0];
    const float* noise = (const float*)d_in[1];
    const int*   f0    = (const int*)d_in[2];
    const int*   f_len = (const int*)d_in[3];
    const int*   t0    = (const int*)d_in[4];
    const int*   t_len = (const int*)d_in[5];
    float* out = (float*)d_out;

    specaug_kernel<<<NBLOCKS, 128, 0, stream>>>(x, noise, f0, f_len, t0, t_len, out);
}

// Round 8
// 98.761 us; speedup vs baseline: 1.1044x; 1.1044x over previous
//
#include <hip/hip_runtime.h>
#include <hip/hip_bf16.h>

// SpecAugment: out = (x + noise*0.04) masked by per-sample freq/time zero masks.
// x, noise: [B=128, C=3, F=128, T=1000] f32. f0/f_len: [B,2], t0/t_len: [B,2] i32.
// Memory-bound. R7 showed misaligned block footprints cost FETCH/WRITE bytes
// (rows are 4000B, not 128B-multiples). This round: block i owns the i-th
// contiguous 4096B chunk of the FLAT array — perfect 128B alignment, zero
// idle lanes (48000 x 256 = NV4 exactly). Row/f/b via magic-mul divide.
// fmask handled per-lane; fully-masked waves exec-mask away their loads.

#define B 128
#define C 3
#define Fd 128
#define T 1000
#define NOISE_STD 0.04f

typedef float  f32x4 __attribute__((ext_vector_type(4)));
typedef int    i32x2 __attribute__((ext_vector_type(2)));

constexpr int ROWS       = B * C * Fd;        // 49152
constexpr int V4_PER_ROW = T / 4;             // 250
constexpr int NV4        = ROWS * V4_PER_ROW; // 12,288,000
constexpr int NBLOCKS    = NV4 / 256;         // 48000 exactly

__global__ __launch_bounds__(256) void specaug_kernel(
    const float* __restrict__ x, const float* __restrict__ noise,
    const int* __restrict__ f0, const int* __restrict__ f_len,
    const int* __restrict__ t0, const int* __restrict__ t_len,
    float* __restrict__ out)
{
    const int i = blockIdx.x * 256 + threadIdx.x;     // flat float4 index

    const unsigned row = (unsigned)i / (unsigned)V4_PER_ROW;   // magic-mul
    const int rem = i - (int)row * V4_PER_ROW;                 // i % 250
    const int b   = (int)(row / (unsigned)(C * Fd));           // magic-mul
    const int f   = (int)(row & (Fd - 1));                     // row % 128

    const i32x2 fa = reinterpret_cast<const i32x2*>(f0)[b];
    const i32x2 fl = reinterpret_cast<const i32x2*>(f_len)[b];
    const bool fmask = (f >= fa.x && f < fa.x + fl.x) ||
                       (f >= fa.y && f < fa.y + fl.y);

    f32x4 ov = {0.f, 0.f, 0.f, 0.f};

    if (!fmask) {
        const i32x2 ta = reinterpret_cast<const i32x2*>(t0)[b];
        const i32x2 tl = reinterpret_cast<const i32x2*>(t_len)[b];

        const f32x4 xv = reinterpret_cast<const f32x4*>(x)[i];
        const f32x4 nv = reinterpret_cast<const f32x4*>(noise)[i];

        const int t = rem * 4;
#pragma unroll
        for (int k = 0; k < 4; ++k) {
            const int tt = t + k;
            const bool tmask = (tt >= ta.x && tt < ta.x + tl.x) ||
                               (tt >= ta.y && tt < ta.y + tl.y);
            ov[k] = tmask ? 0.f : fmaf(nv[k], NOISE_STD, xv[k]);
        }
    }

    reinterpret_cast<f32x4*>(out)[i] = ov;
}

extern "C" void kernel_launch(void* const* d_in, const int* in_sizes, int n_in,
                              void* d_out, int out_size, void* d_ws, size_t ws_size,
                              hipStream_t stream)
{
    const float* x     = (const float*)d_in[0];
    const float* noise = (const float*)d_in[1];
    const int*   f0    = (const int*)d_in[2];
    const int*   f_len = (const int*)d_in[3];
    const int*   t0    = (const int*)d_in[4];
    const int*   t_len = (const int*)d_in[5];
    float* out = (float*)d_out;

    specaug_kernel<<<NBLOCKS, 256, 0, stream>>>(x, noise, f0, f_len, t0, t_len, out);
}